// Round 5
// baseline (825.864 us; speedup 1.0000x reference)
//
#include <hip/hip_runtime.h>
#include <cstdint>
#include <cstddef>

#define BB 128
#define SS 256
#define LL 10
#define NTAGS 32
#define TAG_START 30
#define TAG_END 31
#define WDIM 100
#define CDIM 30
#define NFILT 30
#define HDIM 100
#define KIN 130      // LSTM_IN = WDIM + FILT
#define GDIM 400     // 4*H
#define NEGV -10000.0f

__device__ __forceinline__ float sigm(float x) { return 1.0f / (1.0f + __expf(-x)); }
__device__ __forceinline__ float tanh_fast(float x) { return 2.0f / (1.0f + __expf(-2.0f * x)) - 1.0f; }

// ---------------- K1a: word embedding gather -> x[:, 0:100] ----------------
__global__ void k_word(const float* __restrict__ wemb, const int* __restrict__ wx,
                       float* __restrict__ x) {
  int idx = blockIdx.x * blockDim.x + threadIdx.x;
  if (idx >= BB * SS * WDIM) return;
  int token = idx / WDIM;
  int d = idx - token * WDIM;
  x[(size_t)token * KIN + d] = wemb[(size_t)wx[token] * WDIM + d];
}

// ---------------- K1b: char conv + max-pool -> x[:, 100:130] ----------------
__global__ __launch_bounds__(64) void k_charconv(const float* __restrict__ cemb,
                                                 const float* __restrict__ convw,
                                                 const float* __restrict__ convb,
                                                 const int* __restrict__ cx,
                                                 float* __restrict__ x) {
  int token = blockIdx.x;
  int tid = threadIdx.x;
  __shared__ float e[LL * CDIM];
  __shared__ int ci[LL];
  if (tid < LL) ci[tid] = cx[token * LL + tid];
  __syncthreads();
  for (int i = tid; i < LL * CDIM; i += 64) {
    int l = i / CDIM, c = i - l * CDIM;
    e[i] = cemb[ci[l] * CDIM + c];
  }
  __syncthreads();
  if (tid < NFILT) {
    int f = tid;
    float d0[LL], d1[LL], d2[LL];
#pragma unroll
    for (int l = 0; l < LL; l++) { d0[l] = 0.f; d1[l] = 0.f; d2[l] = 0.f; }
    for (int c = 0; c < CDIM; c++) {
      float w0 = convw[(f * 3 + 0) * CDIM + c];
      float w1 = convw[(f * 3 + 1) * CDIM + c];
      float w2 = convw[(f * 3 + 2) * CDIM + c];
#pragma unroll
      for (int l = 0; l < LL; l++) {
        float ev = e[l * CDIM + c];
        d0[l] += ev * w0; d1[l] += ev * w1; d2[l] += ev * w2;
      }
    }
    float bias = convb[f];
    float m = -3.0e38f;
#pragma unroll
    for (int h = 0; h < LL + 2; h++) {
      float acc = bias;
      int j0 = h - 2, j1 = h - 1, j2 = h;
      if (j0 >= 0 && j0 < LL) acc += d0[j0];
      if (j1 >= 0 && j1 < LL) acc += d1[j1];
      if (j2 >= 0 && j2 < LL) acc += d2[j2];
      m = fmaxf(m, acc);
    }
    x[(size_t)token * KIN + WDIM + f] = m;
  }
}

// ---------------- K2: pre = x @ wih^T + (bih+bhh) for both directions ----------------
__global__ __launch_bounds__(256) void k_pregemm(
    const float* __restrict__ x,
    const float* __restrict__ wihF, const float* __restrict__ wihB,
    const float* __restrict__ bihF, const float* __restrict__ bhhF,
    const float* __restrict__ bihB, const float* __restrict__ bhhB,
    float* __restrict__ preF, float* __restrict__ preB) {
  __shared__ __align__(16) float As[64 * 68];  // [k][m], stride 68
  __shared__ __align__(16) float Bs[64 * 68];  // [k][n], stride 68
  int m0 = blockIdx.x * 64;
  int n0 = blockIdx.y * 64;
  int tid = threadIdx.x;
  int tx = tid & 15, ty = tid >> 4;
  float acc[4][4] = {};

  for (int ph = 0; ph < 2; ph++) {
    if (ph) __syncthreads();
#pragma unroll
    for (int p = 0; p < 4; p++) {
      int idx = p * 256 + tid;
      int k = idx & 63, r = idx >> 6;
      As[k * 68 + r] = x[(size_t)(m0 + r) * KIN + ph * 64 + k];
      int ng = n0 + r;
      float v = 0.f;
      if (ng < 2 * GDIM) {
        const float* wr = (ng < GDIM) ? (wihF + (size_t)ng * KIN)
                                      : (wihB + (size_t)(ng - GDIM) * KIN);
        v = wr[ph * 64 + k];
      }
      Bs[k * 68 + r] = v;
    }
    __syncthreads();
#pragma unroll 4
    for (int k = 0; k < 64; k++) {
      float4 a = *(const float4*)&As[k * 68 + tx * 4];
      float4 b = *(const float4*)&Bs[k * 68 + ty * 4];
      acc[0][0] += a.x * b.x; acc[0][1] += a.x * b.y; acc[0][2] += a.x * b.z; acc[0][3] += a.x * b.w;
      acc[1][0] += a.y * b.x; acc[1][1] += a.y * b.y; acc[1][2] += a.y * b.z; acc[1][3] += a.y * b.w;
      acc[2][0] += a.z * b.x; acc[2][1] += a.z * b.y; acc[2][2] += a.z * b.z; acc[2][3] += a.z * b.w;
      acc[3][0] += a.w * b.x; acc[3][1] += a.w * b.y; acc[3][2] += a.w * b.z; acc[3][3] += a.w * b.w;
    }
  }

  // K tail: k = 128, 129
#pragma unroll
  for (int kg = 128; kg < 130; kg++) {
    float av[4], bv[4];
#pragma unroll
    for (int i = 0; i < 4; i++) av[i] = x[(size_t)(m0 + tx * 4 + i) * KIN + kg];
#pragma unroll
    for (int jj = 0; jj < 4; jj++) {
      int ng = n0 + ty * 4 + jj;
      float v = 0.f;
      if (ng < 2 * GDIM) {
        const float* wr = (ng < GDIM) ? (wihF + (size_t)ng * KIN)
                                      : (wihB + (size_t)(ng - GDIM) * KIN);
        v = wr[kg];
      }
      bv[jj] = v;
    }
#pragma unroll
    for (int i = 0; i < 4; i++)
#pragma unroll
      for (int jj = 0; jj < 4; jj++) acc[i][jj] += av[i] * bv[jj];
  }

  int nbase = n0 + ty * 4;
  if (nbase < 2 * GDIM) {
    int dir = nbase >= GDIM;
    int jb = dir ? nbase - GDIM : nbase;
    float* dst = dir ? preB : preF;
    const float* b1 = dir ? bihB : bihF;
    const float* b2 = dir ? bhhB : bhhF;
    float bias[4];
#pragma unroll
    for (int jj = 0; jj < 4; jj++) bias[jj] = b1[jb + jj] + b2[jb + jj];
#pragma unroll
    for (int i = 0; i < 4; i++) {
      int m = m0 + tx * 4 + i;
      float4 o = make_float4(acc[i][0] + bias[0], acc[i][1] + bias[1],
                             acc[i][2] + bias[2], acc[i][3] + bias[3]);
      *(float4*)&dst[(size_t)m * GDIM + jb] = o;
    }
  }
}

// ---------------- K3: recurrent LSTM scan, block per (batch, dir) ----------------
// K-split design: 1024 threads. Group A (tid<400) computes gate row r=tid over
// k in [0,52); group B (512<=tid<912) computes row r=tid-512 over k in [48,100)
// with its first float4 zeroed (no double count). Per-thread weights = 13
// float4 = 52 VGPRs -> stays in the known-good <=~84 VGPR codegen regime
// WITHOUT __launch_bounds__ min-waves arg (which correlated with R3/R4 NaNs).
// Partial dots meet in LDS gpart[800]; gate threads (tid<100) sum pairs.
// All hsh reads are wave-uniform-address ds_read_b128 -> LDS broadcast,
// conflict-free. Plain __syncthreads throughout (proven structure).
__global__ __launch_bounds__(1024) void k_lstm(
    const float* __restrict__ preF, const float* __restrict__ preB,
    const float* __restrict__ whhF, const float* __restrict__ whhB,
    float* __restrict__ hbuf) {
  int blk = blockIdx.x;
  int dir = blk >> 7;   // 0 fwd, 1 bwd
  int b = blk & 127;
  const float* pre = dir ? preB : preF;
  const float* whh = dir ? whhB : whhF;
  int tid = threadIdx.x;
  int grp = tid >> 9;        // 0: k in [0,52), 1: k in [48,100)
  int r = tid & 511;         // gate row
  bool act = (r < GDIM);
  int rc = act ? r : 0;
  int kb = grp * 48;

  float4 wv[13];
  {
    const float4* w4 = (const float4*)(whh + (size_t)rc * HDIM + kb);
#pragma unroll
    for (int k = 0; k < 13; k++) wv[k] = w4[k];
    if (grp) wv[0] = make_float4(0.f, 0.f, 0.f, 0.f);  // avoid double-count k 48..51
  }

  __shared__ __align__(16) float hsh[2][104];
  __shared__ float gpart[2 * GDIM];
  if (tid < HDIM) hsh[0][tid] = 0.f;
  float c = 0.f;

  const float* pb0 = pre + ((size_t)b * SS + (dir ? (SS - 1) : 0)) * GDIM + rc;
  const intptr_t pstep = dir ? -(intptr_t)GDIM : (intptr_t)GDIM;
  float p0 = 0.f, p1 = 0.f;
  if (act && grp == 0) { p0 = pb0[0]; p1 = pb0[pstep]; }
  __syncthreads();

  int cur = 0;
  for (int step = 0; step < SS; step++) {
    float p2 = 0.f;
    if (act && grp == 0) {
      int tn = (step + 2 < SS) ? (step + 2) : (SS - 1);
      p2 = pb0[(intptr_t)tn * pstep];
    }
    if (act) {
      const float4* h4 = (const float4*)&hsh[cur][kb];
      float acc = grp ? 0.f : p0;   // (p0 + sum[0,52)) + sum[52,100): ~R1 order
#pragma unroll
      for (int k = 0; k < 13; k++) {
        float4 hv = h4[k];
        acc += hv.x * wv[k].x + hv.y * wv[k].y + hv.z * wv[k].z + hv.w * wv[k].w;
      }
      gpart[grp * GDIM + r] = acc;
    }
    __syncthreads();
    if (tid < HDIM) {
      int j = tid;
      float gi = gpart[j] + gpart[GDIM + j];
      float gf = gpart[HDIM + j] + gpart[GDIM + HDIM + j];
      float gg = gpart[2 * HDIM + j] + gpart[GDIM + 2 * HDIM + j];
      float go = gpart[3 * HDIM + j] + gpart[GDIM + 3 * HDIM + j];
      float ig = sigm(gi), fg = sigm(gf), g2 = tanh_fast(gg), og = sigm(go);
      c = fg * c + ig * g2;
      float h = og * tanh_fast(c);
      hsh[cur ^ 1][j] = h;
      int t = dir ? (SS - 1 - step) : step;
      hbuf[((size_t)b * SS + t) * (2 * HDIM) + dir * HDIM + j] = h;
    }
    __syncthreads();
    p0 = p1; p1 = p2;
    cur ^= 1;
  }
}

// ---------------- K4: emission = [h_f,h_b] @ proj_w^T + proj_b ----------------
__global__ void k_proj(const float* __restrict__ hbuf, const float* __restrict__ pw,
                       const float* __restrict__ pb, float* __restrict__ em) {
  int idx = blockIdx.x * blockDim.x + threadIdx.x;  // token*32 + tag
  if (idx >= BB * SS * NTAGS) return;
  int token = idx >> 5, tag = idx & 31;
  const float4* h4 = (const float4*)(hbuf + (size_t)token * 2 * HDIM);
  const float4* w4 = (const float4*)(pw + (size_t)tag * 2 * HDIM);
  float acc = pb[tag];
#pragma unroll 10
  for (int k = 0; k < 50; k++) {
    float4 hv = h4[k], wv = w4[k];
    acc += hv.x * wv.x + hv.y * wv.y + hv.z * wv.z + hv.w * wv.w;
  }
  em[idx] = acc;
}

// ---------------- K5: gold path score per batch ----------------
__global__ __launch_bounds__(64) void k_score(const float* __restrict__ em,
                                              const float* __restrict__ trans,
                                              const int* __restrict__ y,
                                              const int* __restrict__ mask,
                                              float* __restrict__ scoreY) {
  int b = blockIdx.x, l = threadIdx.x;
  float acc = 0.f;
  for (int s = l; s < SS; s += 64) {
    int curt = y[b * SS + s];
    int prevt = (s == 0) ? TAG_START : y[b * SS + s - 1];
    float mk = (float)mask[b * SS + s];
    acc += (em[((size_t)b * SS + s) * NTAGS + curt] + trans[prevt * NTAGS + curt]) * mk;
  }
#pragma unroll
  for (int off = 32; off > 0; off >>= 1) acc += __shfl_down(acc, off);
  if (l == 0) scoreY[b] = acc + trans[y[b * SS + SS - 1] * NTAGS + TAG_END];
}

// ---------------- K6: CRF forward (partition function) + loss ----------------
__global__ __launch_bounds__(64) void k_crf(const float* __restrict__ em,
                                            const float* __restrict__ trans,
                                            const int* __restrict__ mask,
                                            const float* __restrict__ scoreY,
                                            float* __restrict__ out) {
  int g = threadIdx.x >> 5;
  int j = threadIdx.x & 31;
  int b = blockIdx.x * 2 + g;
  float tcol[NTAGS];
#pragma unroll
  for (int i = 0; i < NTAGS; i++) tcol[i] = trans[i * NTAGS + j];
  float la = (j == TAG_START) ? 0.f : NEGV;
  __shared__ float lash[2][NTAGS];
  for (int s = 0; s < SS; s++) {
    lash[g][j] = la;
    __syncthreads();
    float emv = em[((size_t)b * SS + s) * NTAGS + j];
    float m = -3.0e38f;
#pragma unroll
    for (int i = 0; i < NTAGS; i++) m = fmaxf(m, lash[g][i] + tcol[i]);
    float sum = 0.f;
#pragma unroll
    for (int i = 0; i < NTAGS; i++) sum += __expf(lash[g][i] + tcol[i] - m);
    float la2 = m + __logf(sum) + emv;
    float mk = (float)mask[b * SS + s];
    la = la2 * mk + la * (1.f - mk);
    __syncthreads();
  }
  la += trans[j * NTAGS + TAG_END];
  lash[g][j] = la;
  __syncthreads();
  float m = -3.0e38f;
#pragma unroll
  for (int i = 0; i < NTAGS; i++) m = fmaxf(m, lash[g][i]);
  float sum = 0.f;
#pragma unroll
  for (int i = 0; i < NTAGS; i++) sum += __expf(lash[g][i] - m);
  float total = m + __logf(sum);
  if (j == 0) atomicAdd(out, (total - scoreY[b]) * (1.0f / BB));
}

extern "C" void kernel_launch(void* const* d_in, const int* in_sizes, int n_in,
                              void* d_out, int out_size, void* d_ws, size_t ws_size,
                              hipStream_t stream) {
  const float* word_emb = (const float*)d_in[0];
  const float* char_emb = (const float*)d_in[1];
  const float* conv_w   = (const float*)d_in[2];
  const float* conv_b   = (const float*)d_in[3];
  const float* wih_f    = (const float*)d_in[4];
  const float* whh_f    = (const float*)d_in[5];
  const float* bih_f    = (const float*)d_in[6];
  const float* bhh_f    = (const float*)d_in[7];
  const float* wih_b    = (const float*)d_in[8];
  const float* whh_b    = (const float*)d_in[9];
  const float* bih_b    = (const float*)d_in[10];
  const float* bhh_b    = (const float*)d_in[11];
  const float* proj_w   = (const float*)d_in[12];
  const float* proj_b   = (const float*)d_in[13];
  const float* trans    = (const float*)d_in[14];
  const int* word_x     = (const int*)d_in[15];
  const int* char_x     = (const int*)d_in[16];
  const int* y          = (const int*)d_in[17];
  const int* mask       = (const int*)d_in[18];
  float* out = (float*)d_out;

  float* ws = (float*)d_ws;
  float* x      = ws;                                  // 32768*130
  float* preF   = x + (size_t)BB * SS * KIN;           // 32768*400
  float* preB   = preF + (size_t)BB * SS * GDIM;       // 32768*400
  float* hbuf   = preB + (size_t)BB * SS * GDIM;       // 32768*200
  float* em     = hbuf + (size_t)BB * SS * 2 * HDIM;   // 32768*32
  float* scoreY = em + (size_t)BB * SS * NTAGS;        // 128

  hipMemsetAsync(d_out, 0, sizeof(float), stream);
  k_word<<<(BB * SS * WDIM + 255) / 256, 256, 0, stream>>>(word_emb, word_x, x);
  k_charconv<<<BB * SS, 64, 0, stream>>>(char_emb, conv_w, conv_b, char_x, x);
  k_pregemm<<<dim3(BB * SS / 64, 13), 256, 0, stream>>>(x, wih_f, wih_b, bih_f, bhh_f,
                                                        bih_b, bhh_b, preF, preB);
  k_lstm<<<256, 1024, 0, stream>>>(preF, preB, whh_f, whh_b, hbuf);
  k_proj<<<(BB * SS * NTAGS + 255) / 256, 256, 0, stream>>>(hbuf, proj_w, proj_b, em);
  k_score<<<BB, 64, 0, stream>>>(em, trans, y, mask, scoreY);
  k_crf<<<BB / 2, 64, 0, stream>>>(em, trans, mask, scoreY, out);
}

// Round 6
// 735.236 us; speedup vs baseline: 1.1233x; 1.1233x over previous
//
#include <hip/hip_runtime.h>
#include <hip/hip_fp16.h>
#include <cstdint>
#include <cstddef>

#define BB 128
#define SS 256
#define LL 10
#define NTAGS 32
#define TAG_START 30
#define TAG_END 31
#define WDIM 100
#define CDIM 30
#define NFILT 30
#define HDIM 100
#define KIN 130      // LSTM_IN = WDIM + FILT
#define GDIM 400     // 4*H
#define NEGV -10000.0f

__device__ __forceinline__ float sigm(float x) { return 1.0f / (1.0f + __expf(-x)); }
__device__ __forceinline__ float tanh_fast(float x) { return 2.0f / (1.0f + __expf(-2.0f * x)) - 1.0f; }

// ---------------- K1a: word embedding gather -> x[:, 0:100] ----------------
__global__ void k_word(const float* __restrict__ wemb, const int* __restrict__ wx,
                       float* __restrict__ x) {
  int idx = blockIdx.x * blockDim.x + threadIdx.x;
  if (idx >= BB * SS * WDIM) return;
  int token = idx / WDIM;
  int d = idx - token * WDIM;
  x[(size_t)token * KIN + d] = wemb[(size_t)wx[token] * WDIM + d];
}

// ---------------- K1b: char conv + max-pool -> x[:, 100:130] ----------------
__global__ __launch_bounds__(64) void k_charconv(const float* __restrict__ cemb,
                                                 const float* __restrict__ convw,
                                                 const float* __restrict__ convb,
                                                 const int* __restrict__ cx,
                                                 float* __restrict__ x) {
  int token = blockIdx.x;
  int tid = threadIdx.x;
  __shared__ float e[LL * CDIM];
  __shared__ int ci[LL];
  if (tid < LL) ci[tid] = cx[token * LL + tid];
  __syncthreads();
  for (int i = tid; i < LL * CDIM; i += 64) {
    int l = i / CDIM, c = i - l * CDIM;
    e[i] = cemb[ci[l] * CDIM + c];
  }
  __syncthreads();
  if (tid < NFILT) {
    int f = tid;
    float d0[LL], d1[LL], d2[LL];
#pragma unroll
    for (int l = 0; l < LL; l++) { d0[l] = 0.f; d1[l] = 0.f; d2[l] = 0.f; }
    for (int c = 0; c < CDIM; c++) {
      float w0 = convw[(f * 3 + 0) * CDIM + c];
      float w1 = convw[(f * 3 + 1) * CDIM + c];
      float w2 = convw[(f * 3 + 2) * CDIM + c];
#pragma unroll
      for (int l = 0; l < LL; l++) {
        float ev = e[l * CDIM + c];
        d0[l] += ev * w0; d1[l] += ev * w1; d2[l] += ev * w2;
      }
    }
    float bias = convb[f];
    float m = -3.0e38f;
#pragma unroll
    for (int h = 0; h < LL + 2; h++) {
      float acc = bias;
      int j0 = h - 2, j1 = h - 1, j2 = h;
      if (j0 >= 0 && j0 < LL) acc += d0[j0];
      if (j1 >= 0 && j1 < LL) acc += d1[j1];
      if (j2 >= 0 && j2 < LL) acc += d2[j2];
      m = fmaxf(m, acc);
    }
    x[(size_t)token * KIN + WDIM + f] = m;
  }
}

// ---------------- K2: pre = x @ wih^T + (bih+bhh) for both directions ----------------
__global__ __launch_bounds__(256) void k_pregemm(
    const float* __restrict__ x,
    const float* __restrict__ wihF, const float* __restrict__ wihB,
    const float* __restrict__ bihF, const float* __restrict__ bhhF,
    const float* __restrict__ bihB, const float* __restrict__ bhhB,
    float* __restrict__ preF, float* __restrict__ preB) {
  __shared__ __align__(16) float As[64 * 68];  // [k][m], stride 68
  __shared__ __align__(16) float Bs[64 * 68];  // [k][n], stride 68
  int m0 = blockIdx.x * 64;
  int n0 = blockIdx.y * 64;
  int tid = threadIdx.x;
  int tx = tid & 15, ty = tid >> 4;
  float acc[4][4] = {};

  for (int ph = 0; ph < 2; ph++) {
    if (ph) __syncthreads();
#pragma unroll
    for (int p = 0; p < 4; p++) {
      int idx = p * 256 + tid;
      int k = idx & 63, r = idx >> 6;
      As[k * 68 + r] = x[(size_t)(m0 + r) * KIN + ph * 64 + k];
      int ng = n0 + r;
      float v = 0.f;
      if (ng < 2 * GDIM) {
        const float* wr = (ng < GDIM) ? (wihF + (size_t)ng * KIN)
                                      : (wihB + (size_t)(ng - GDIM) * KIN);
        v = wr[ph * 64 + k];
      }
      Bs[k * 68 + r] = v;
    }
    __syncthreads();
#pragma unroll 4
    for (int k = 0; k < 64; k++) {
      float4 a = *(const float4*)&As[k * 68 + tx * 4];
      float4 b = *(const float4*)&Bs[k * 68 + ty * 4];
      acc[0][0] += a.x * b.x; acc[0][1] += a.x * b.y; acc[0][2] += a.x * b.z; acc[0][3] += a.x * b.w;
      acc[1][0] += a.y * b.x; acc[1][1] += a.y * b.y; acc[1][2] += a.y * b.z; acc[1][3] += a.y * b.w;
      acc[2][0] += a.z * b.x; acc[2][1] += a.z * b.y; acc[2][2] += a.z * b.z; acc[2][3] += a.z * b.w;
      acc[3][0] += a.w * b.x; acc[3][1] += a.w * b.y; acc[3][2] += a.w * b.z; acc[3][3] += a.w * b.w;
    }
  }

  // K tail: k = 128, 129
#pragma unroll
  for (int kg = 128; kg < 130; kg++) {
    float av[4], bv[4];
#pragma unroll
    for (int i = 0; i < 4; i++) av[i] = x[(size_t)(m0 + tx * 4 + i) * KIN + kg];
#pragma unroll
    for (int jj = 0; jj < 4; jj++) {
      int ng = n0 + ty * 4 + jj;
      float v = 0.f;
      if (ng < 2 * GDIM) {
        const float* wr = (ng < GDIM) ? (wihF + (size_t)ng * KIN)
                                      : (wihB + (size_t)(ng - GDIM) * KIN);
        v = wr[kg];
      }
      bv[jj] = v;
    }
#pragma unroll
    for (int i = 0; i < 4; i++)
#pragma unroll
      for (int jj = 0; jj < 4; jj++) acc[i][jj] += av[i] * bv[jj];
  }

  int nbase = n0 + ty * 4;
  if (nbase < 2 * GDIM) {
    int dir = nbase >= GDIM;
    int jb = dir ? nbase - GDIM : nbase;
    float* dst = dir ? preB : preF;
    const float* b1 = dir ? bihB : bihF;
    const float* b2 = dir ? bhhB : bhhF;
    float bias[4];
#pragma unroll
    for (int jj = 0; jj < 4; jj++) bias[jj] = b1[jb + jj] + b2[jb + jj];
#pragma unroll
    for (int i = 0; i < 4; i++) {
      int m = m0 + tx * 4 + i;
      float4 o = make_float4(acc[i][0] + bias[0], acc[i][1] + bias[1],
                             acc[i][2] + bias[2], acc[i][3] + bias[3]);
      *(float4*)&dst[(size_t)m * GDIM + jb] = o;
    }
  }
}

// ---------------- K3: recurrent LSTM scan, block per (batch, dir) ----------------
// f16-weight design: each gate-row thread holds its whh row as 50 packed
// __half2 = 50 VGPRs (fp32 needed 100 -> always spilled under the compiler's
// VGPR budget; f16 fits under the ~84 cap observed for 512-thread blocks).
// (float)half * float fuses to v_fma_mix_f32. f16 rel err 2^-11 on 0.1-scale
// weights -> negligible vs threshold. Proven skeleton: plain __syncthreads,
// 2-deep pre prefetch, immediate h store. NO launch_bounds min-waves arg
// (correlated with R3/R4 NaNs).
__global__ __launch_bounds__(512) void k_lstm(
    const float* __restrict__ preF, const float* __restrict__ preB,
    const float* __restrict__ whhF, const float* __restrict__ whhB,
    float* __restrict__ hbuf) {
  int blk = blockIdx.x;
  int dir = blk >> 7;   // 0 fwd, 1 bwd
  int b = blk & 127;
  const float* pre = dir ? preB : preF;
  const float* whh = dir ? whhB : whhF;
  int j = threadIdx.x;
  bool act = (j < GDIM);
  int jc = act ? j : (GDIM - 1);

  __half2 wp[50];   // 100 f16 weights = 50 VGPRs
  {
    const float2* w2 = (const float2*)(whh + (size_t)jc * HDIM);
#pragma unroll
    for (int k = 0; k < 50; k++) {
      float2 w = w2[k];
      wp[k] = __floats2half2_rn(w.x, w.y);
    }
  }

  __shared__ __align__(16) float hsh[2][HDIM];
  __shared__ float gsh[GDIM];
  if (j < HDIM) hsh[0][j] = 0.f;
  float c = 0.f;

  const float* pbase = pre + ((size_t)b * SS + (dir ? (SS - 1) : 0)) * GDIM + jc;
  const intptr_t pstep = dir ? -(intptr_t)GDIM : (intptr_t)GDIM;

  float p0 = pbase[0];
  float p1 = pbase[pstep];
  __syncthreads();

  int cur = 0;
  for (int step = 0; step < SS; step++) {
    int tn = (step + 2 < SS) ? (step + 2) : (SS - 1);
    float p2 = pbase[(intptr_t)tn * pstep];

    {
      const float4* h4 = (const float4*)&hsh[cur][0];
      float acc = p0;  // sequential chain: ~R1 summation order
#pragma unroll
      for (int kk = 0; kk < 25; kk++) {
        float4 hv = h4[kk];
        __half2 w0 = wp[2 * kk], w1 = wp[2 * kk + 1];
        acc = fmaf(__low2float(w0), hv.x, acc);
        acc = fmaf(__high2float(w0), hv.y, acc);
        acc = fmaf(__low2float(w1), hv.z, acc);
        acc = fmaf(__high2float(w1), hv.w, acc);
      }
      if (act) gsh[j] = acc;
    }
    __syncthreads();
    if (j < HDIM) {
      float ig = sigm(gsh[j]);
      float fg = sigm(gsh[j + HDIM]);
      float gg = tanh_fast(gsh[j + 2 * HDIM]);
      float og = sigm(gsh[j + 3 * HDIM]);
      c = fg * c + ig * gg;
      float h = og * tanh_fast(c);
      hsh[cur ^ 1][j] = h;
      int t = dir ? (SS - 1 - step) : step;
      hbuf[((size_t)b * SS + t) * (2 * HDIM) + dir * HDIM + j] = h;
    }
    __syncthreads();
    p0 = p1; p1 = p2;
    cur ^= 1;
  }
}

// ---------------- K4: emission = [h_f,h_b] @ proj_w^T + proj_b ----------------
__global__ void k_proj(const float* __restrict__ hbuf, const float* __restrict__ pw,
                       const float* __restrict__ pb, float* __restrict__ em) {
  int idx = blockIdx.x * blockDim.x + threadIdx.x;  // token*32 + tag
  if (idx >= BB * SS * NTAGS) return;
  int token = idx >> 5, tag = idx & 31;
  const float4* h4 = (const float4*)(hbuf + (size_t)token * 2 * HDIM);
  const float4* w4 = (const float4*)(pw + (size_t)tag * 2 * HDIM);
  float acc = pb[tag];
#pragma unroll 10
  for (int k = 0; k < 50; k++) {
    float4 hv = h4[k], wv = w4[k];
    acc += hv.x * wv.x + hv.y * wv.y + hv.z * wv.z + hv.w * wv.w;
  }
  em[idx] = acc;
}

// ---------------- K5: gold path score per batch ----------------
__global__ __launch_bounds__(64) void k_score(const float* __restrict__ em,
                                              const float* __restrict__ trans,
                                              const int* __restrict__ y,
                                              const int* __restrict__ mask,
                                              float* __restrict__ scoreY) {
  int b = blockIdx.x, l = threadIdx.x;
  float acc = 0.f;
  for (int s = l; s < SS; s += 64) {
    int curt = y[b * SS + s];
    int prevt = (s == 0) ? TAG_START : y[b * SS + s - 1];
    float mk = (float)mask[b * SS + s];
    acc += (em[((size_t)b * SS + s) * NTAGS + curt] + trans[prevt * NTAGS + curt]) * mk;
  }
#pragma unroll
  for (int off = 32; off > 0; off >>= 1) acc += __shfl_down(acc, off);
  if (l == 0) scoreY[b] = acc + trans[y[b * SS + SS - 1] * NTAGS + TAG_END];
}

// ---------------- K6: CRF forward (partition function) + loss ----------------
__global__ __launch_bounds__(64) void k_crf(const float* __restrict__ em,
                                            const float* __restrict__ trans,
                                            const int* __restrict__ mask,
                                            const float* __restrict__ scoreY,
                                            float* __restrict__ out) {
  int g = threadIdx.x >> 5;
  int j = threadIdx.x & 31;
  int b = blockIdx.x * 2 + g;
  float tcol[NTAGS];
#pragma unroll
  for (int i = 0; i < NTAGS; i++) tcol[i] = trans[i * NTAGS + j];
  float la = (j == TAG_START) ? 0.f : NEGV;
  __shared__ float lash[2][NTAGS];
  for (int s = 0; s < SS; s++) {
    lash[g][j] = la;
    __syncthreads();
    float emv = em[((size_t)b * SS + s) * NTAGS + j];
    float m = -3.0e38f;
#pragma unroll
    for (int i = 0; i < NTAGS; i++) m = fmaxf(m, lash[g][i] + tcol[i]);
    float sum = 0.f;
#pragma unroll
    for (int i = 0; i < NTAGS; i++) sum += __expf(lash[g][i] + tcol[i] - m);
    float la2 = m + __logf(sum) + emv;
    float mk = (float)mask[b * SS + s];
    la = la2 * mk + la * (1.f - mk);
    __syncthreads();
  }
  la += trans[j * NTAGS + TAG_END];
  lash[g][j] = la;
  __syncthreads();
  float m = -3.0e38f;
#pragma unroll
  for (int i = 0; i < NTAGS; i++) m = fmaxf(m, lash[g][i]);
  float sum = 0.f;
#pragma unroll
  for (int i = 0; i < NTAGS; i++) sum += __expf(lash[g][i] - m);
  float total = m + __logf(sum);
  if (j == 0) atomicAdd(out, (total - scoreY[b]) * (1.0f / BB));
}

extern "C" void kernel_launch(void* const* d_in, const int* in_sizes, int n_in,
                              void* d_out, int out_size, void* d_ws, size_t ws_size,
                              hipStream_t stream) {
  const float* word_emb = (const float*)d_in[0];
  const float* char_emb = (const float*)d_in[1];
  const float* conv_w   = (const float*)d_in[2];
  const float* conv_b   = (const float*)d_in[3];
  const float* wih_f    = (const float*)d_in[4];
  const float* whh_f    = (const float*)d_in[5];
  const float* bih_f    = (const float*)d_in[6];
  const float* bhh_f    = (const float*)d_in[7];
  const float* wih_b    = (const float*)d_in[8];
  const float* whh_b    = (const float*)d_in[9];
  const float* bih_b    = (const float*)d_in[10];
  const float* bhh_b    = (const float*)d_in[11];
  const float* proj_w   = (const float*)d_in[12];
  const float* proj_b   = (const float*)d_in[13];
  const float* trans    = (const float*)d_in[14];
  const int* word_x     = (const int*)d_in[15];
  const int* char_x     = (const int*)d_in[16];
  const int* y          = (const int*)d_in[17];
  const int* mask       = (const int*)d_in[18];
  float* out = (float*)d_out;

  float* ws = (float*)d_ws;
  float* x      = ws;                                  // 32768*130
  float* preF   = x + (size_t)BB * SS * KIN;           // 32768*400
  float* preB   = preF + (size_t)BB * SS * GDIM;       // 32768*400
  float* hbuf   = preB + (size_t)BB * SS * GDIM;       // 32768*200
  float* em     = hbuf + (size_t)BB * SS * 2 * HDIM;   // 32768*32
  float* scoreY = em + (size_t)BB * SS * NTAGS;        // 128

  hipMemsetAsync(d_out, 0, sizeof(float), stream);
  k_word<<<(BB * SS * WDIM + 255) / 256, 256, 0, stream>>>(word_emb, word_x, x);
  k_charconv<<<BB * SS, 64, 0, stream>>>(char_emb, conv_w, conv_b, char_x, x);
  k_pregemm<<<dim3(BB * SS / 64, 13), 256, 0, stream>>>(x, wih_f, wih_b, bih_f, bhh_f,
                                                        bih_b, bhh_b, preF, preB);
  k_lstm<<<256, 512, 0, stream>>>(preF, preB, whh_f, whh_b, hbuf);
  k_proj<<<(BB * SS * NTAGS + 255) / 256, 256, 0, stream>>>(hbuf, proj_w, proj_b, em);
  k_score<<<BB, 64, 0, stream>>>(em, trans, y, mask, scoreY);
  k_crf<<<BB / 2, 64, 0, stream>>>(em, trans, mask, scoreY, out);
}

// Round 8
// 723.006 us; speedup vs baseline: 1.1423x; 1.0169x over previous
//
#include <hip/hip_runtime.h>
#include <hip/hip_fp16.h>
#include <cstdint>
#include <cstddef>

#define BB 128
#define SS 256
#define LL 10
#define NTAGS 32
#define TAG_START 30
#define TAG_END 31
#define WDIM 100
#define CDIM 30
#define NFILT 30
#define HDIM 100
#define KIN 130      // LSTM_IN = WDIM + FILT
#define GDIM 400     // 4*H
#define NEGV -10000.0f
#define CTOK 8       // tokens per charconv block

typedef _Float16 h2 __attribute__((ext_vector_type(2)));

__device__ __forceinline__ float sigm(float x) { return 1.0f / (1.0f + __expf(-x)); }
__device__ __forceinline__ float tanh_fast(float x) { return 2.0f / (1.0f + __expf(-2.0f * x)) - 1.0f; }

// ---------------- K1a: word embedding gather -> x[:, 0:100] ----------------
__global__ void k_word(const float* __restrict__ wemb, const int* __restrict__ wx,
                       float* __restrict__ x) {
  int idx = blockIdx.x * blockDim.x + threadIdx.x;
  if (idx >= BB * SS * WDIM) return;
  int token = idx / WDIM;
  int d = idx - token * WDIM;
  x[(size_t)token * KIN + d] = wemb[(size_t)wx[token] * WDIM + d];
}

// ---------------- K1b: char conv + max-pool -> x[:, 100:130] ----------------
// 8 tokens per 256-thread block: tid = (token_in_block<<5) | filter.
__global__ __launch_bounds__(256) void k_charconv(const float* __restrict__ cemb,
                                                  const float* __restrict__ convw,
                                                  const float* __restrict__ convb,
                                                  const int* __restrict__ cx,
                                                  float* __restrict__ x) {
  int blk = blockIdx.x;
  int tid = threadIdx.x;
  int tok8 = tid >> 5;
  int f = tid & 31;
  int token0 = blk * CTOK;
  __shared__ float e[CTOK][LL * CDIM];
  __shared__ int ci[CTOK][LL];
  if (tid < CTOK * LL) {
    int t = tid / LL, l = tid - t * LL;
    ci[t][l] = cx[(token0 + t) * LL + l];
  }
  __syncthreads();
  for (int i = tid; i < CTOK * LL * CDIM; i += 256) {
    int t = i / (LL * CDIM);
    int r = i - t * (LL * CDIM);
    int l = r / CDIM, c = r - l * CDIM;
    e[t][l * CDIM + c] = cemb[ci[t][l] * CDIM + c];
  }
  __syncthreads();
  if (f < NFILT) {
    float d0[LL], d1[LL], d2[LL];
#pragma unroll
    for (int l = 0; l < LL; l++) { d0[l] = 0.f; d1[l] = 0.f; d2[l] = 0.f; }
    const float* et = &e[tok8][0];
    for (int c = 0; c < CDIM; c++) {
      float w0 = convw[(f * 3 + 0) * CDIM + c];
      float w1 = convw[(f * 3 + 1) * CDIM + c];
      float w2 = convw[(f * 3 + 2) * CDIM + c];
#pragma unroll
      for (int l = 0; l < LL; l++) {
        float ev = et[l * CDIM + c];
        d0[l] += ev * w0; d1[l] += ev * w1; d2[l] += ev * w2;
      }
    }
    float bias = convb[f];
    float m = -3.0e38f;
#pragma unroll
    for (int h = 0; h < LL + 2; h++) {
      float acc = bias;
      int j0 = h - 2, j1 = h - 1, j2 = h;
      if (j0 >= 0 && j0 < LL) acc += d0[j0];
      if (j1 >= 0 && j1 < LL) acc += d1[j1];
      if (j2 >= 0 && j2 < LL) acc += d2[j2];
      m = fmaxf(m, acc);
    }
    x[(size_t)(token0 + tok8) * KIN + WDIM + f] = m;
  }
}

// ---------------- K2: pre = x @ wih^T + (bih+bhh) for both directions ----------------
__global__ __launch_bounds__(256) void k_pregemm(
    const float* __restrict__ x,
    const float* __restrict__ wihF, const float* __restrict__ wihB,
    const float* __restrict__ bihF, const float* __restrict__ bhhF,
    const float* __restrict__ bihB, const float* __restrict__ bhhB,
    float* __restrict__ preF, float* __restrict__ preB) {
  __shared__ __align__(16) float As[64 * 68];  // [k][m], stride 68
  __shared__ __align__(16) float Bs[64 * 68];  // [k][n], stride 68
  int m0 = blockIdx.x * 64;
  int n0 = blockIdx.y * 64;
  int tid = threadIdx.x;
  int tx = tid & 15, ty = tid >> 4;
  float acc[4][4] = {};

  for (int ph = 0; ph < 2; ph++) {
    if (ph) __syncthreads();
#pragma unroll
    for (int p = 0; p < 4; p++) {
      int idx = p * 256 + tid;
      int k = idx & 63, r = idx >> 6;
      As[k * 68 + r] = x[(size_t)(m0 + r) * KIN + ph * 64 + k];
      int ng = n0 + r;
      float v = 0.f;
      if (ng < 2 * GDIM) {
        const float* wr = (ng < GDIM) ? (wihF + (size_t)ng * KIN)
                                      : (wihB + (size_t)(ng - GDIM) * KIN);
        v = wr[ph * 64 + k];
      }
      Bs[k * 68 + r] = v;
    }
    __syncthreads();
#pragma unroll 4
    for (int k = 0; k < 64; k++) {
      float4 a = *(const float4*)&As[k * 68 + tx * 4];
      float4 b = *(const float4*)&Bs[k * 68 + ty * 4];
      acc[0][0] += a.x * b.x; acc[0][1] += a.x * b.y; acc[0][2] += a.x * b.z; acc[0][3] += a.x * b.w;
      acc[1][0] += a.y * b.x; acc[1][1] += a.y * b.y; acc[1][2] += a.y * b.z; acc[1][3] += a.y * b.w;
      acc[2][0] += a.z * b.x; acc[2][1] += a.z * b.y; acc[2][2] += a.z * b.z; acc[2][3] += a.z * b.w;
      acc[3][0] += a.w * b.x; acc[3][1] += a.w * b.y; acc[3][2] += a.w * b.z; acc[3][3] += a.w * b.w;
    }
  }

  // K tail: k = 128, 129
#pragma unroll
  for (int kg = 128; kg < 130; kg++) {
    float av[4], bv[4];
#pragma unroll
    for (int i = 0; i < 4; i++) av[i] = x[(size_t)(m0 + tx * 4 + i) * KIN + kg];
#pragma unroll
    for (int jj = 0; jj < 4; jj++) {
      int ng = n0 + ty * 4 + jj;
      float v = 0.f;
      if (ng < 2 * GDIM) {
        const float* wr = (ng < GDIM) ? (wihF + (size_t)ng * KIN)
                                      : (wihB + (size_t)(ng - GDIM) * KIN);
        v = wr[kg];
      }
      bv[jj] = v;
    }
#pragma unroll
    for (int i = 0; i < 4; i++)
#pragma unroll
      for (int jj = 0; jj < 4; jj++) acc[i][jj] += av[i] * bv[jj];
  }

  int nbase = n0 + ty * 4;
  if (nbase < 2 * GDIM) {
    int dir = nbase >= GDIM;
    int jb = dir ? nbase - GDIM : nbase;
    float* dst = dir ? preB : preF;
    const float* b1 = dir ? bihB : bihF;
    const float* b2 = dir ? bhhB : bhhF;
    float bias[4];
#pragma unroll
    for (int jj = 0; jj < 4; jj++) bias[jj] = b1[jb + jj] + b2[jb + jj];
#pragma unroll
    for (int i = 0; i < 4; i++) {
      int m = m0 + tx * 4 + i;
      float4 o = make_float4(acc[i][0] + bias[0], acc[i][1] + bias[1],
                             acc[i][2] + bias[2], acc[i][3] + bias[3]);
      *(float4*)&dst[(size_t)m * GDIM + jb] = o;
    }
  }
}

// ---------------- K3: recurrent LSTM scan, block per (batch, dir) ----------------
// R6 structure (proven: plain __syncthreads, sequential chain, f16 weights,
// 512 threads) with ONE delta: h is exchanged through LDS as f16, so the
// per-thread broadcast read is 13 ds_read_b128 instead of 25 (LDS pipe was
// the R6 bottleneck: 200 b128 ops/step ~ 2400 cyc). Weights padded to 52
// f16-pairs (last 2 zero) so the 13th read (h[96..103], pad zeros) is
// harmless. MACs via (float)f16 casts -> v_fma_mix. No readlane/fdot2/asm
// (each correlated with a NaN round).
__global__ __launch_bounds__(512) void k_lstm(
    const float* __restrict__ preF, const float* __restrict__ preB,
    const float* __restrict__ whhF, const float* __restrict__ whhB,
    float* __restrict__ hbuf) {
  int blk = blockIdx.x;
  int dir = blk >> 7;   // 0 fwd, 1 bwd
  int b = blk & 127;
  const float* pre = dir ? preB : preF;
  const float* whh = dir ? whhB : whhF;
  int j = threadIdx.x;
  bool act = (j < GDIM);
  int jc = act ? j : (GDIM - 1);

  h2 wp[52];   // 104 f16 weights (last 4 zero) = 52 VGPRs
  {
    const float2* w2 = (const float2*)(whh + (size_t)jc * HDIM);
#pragma unroll
    for (int k = 0; k < 50; k++) {
      float2 w = w2[k];
      h2 hw; hw.x = (_Float16)w.x; hw.y = (_Float16)w.y;
      wp[k] = hw;
    }
    h2 z; z.x = (_Float16)0.f; z.y = (_Float16)0.f;
    wp[50] = z; wp[51] = z;
  }

  __shared__ __align__(16) _Float16 hsh16[2][104];
  __shared__ float gsh[GDIM];
  if (j < 104) { hsh16[0][j] = (_Float16)0.f; hsh16[1][j] = (_Float16)0.f; }
  float c = 0.f;

  const float* pbase = pre + ((size_t)b * SS + (dir ? (SS - 1) : 0)) * GDIM + jc;
  const intptr_t pstep = dir ? -(intptr_t)GDIM : (intptr_t)GDIM;

  float p0 = pbase[0];
  float p1 = pbase[pstep];
  __syncthreads();

  int cur = 0;
  for (int step = 0; step < SS; step++) {
    int tn = (step + 2 < SS) ? (step + 2) : (SS - 1);
    float p2 = pbase[(intptr_t)tn * pstep];

    {
      const uint4* h4 = (const uint4*)&hsh16[cur][0];
      float acc = p0;  // sequential chain: ~R1/R6 summation order
#pragma unroll
      for (int kk = 0; kk < 13; kk++) {
        uint4 hv = h4[kk];
        h2 ha = __builtin_bit_cast(h2, hv.x);
        h2 hb = __builtin_bit_cast(h2, hv.y);
        h2 hc = __builtin_bit_cast(h2, hv.z);
        h2 hd = __builtin_bit_cast(h2, hv.w);
        h2 wa = wp[4 * kk], wb = wp[4 * kk + 1];
        h2 wc = wp[4 * kk + 2], wd = wp[4 * kk + 3];
        acc = fmaf((float)ha.x, (float)wa.x, acc);
        acc = fmaf((float)ha.y, (float)wa.y, acc);
        acc = fmaf((float)hb.x, (float)wb.x, acc);
        acc = fmaf((float)hb.y, (float)wb.y, acc);
        acc = fmaf((float)hc.x, (float)wc.x, acc);
        acc = fmaf((float)hc.y, (float)wc.y, acc);
        acc = fmaf((float)hd.x, (float)wd.x, acc);
        acc = fmaf((float)hd.y, (float)wd.y, acc);
      }
      if (act) gsh[j] = acc;
    }
    __syncthreads();
    if (j < HDIM) {
      float ig = sigm(gsh[j]);
      float fg = sigm(gsh[j + HDIM]);
      float gg = tanh_fast(gsh[j + 2 * HDIM]);
      float og = sigm(gsh[j + 3 * HDIM]);
      c = fg * c + ig * gg;
      float h = og * tanh_fast(c);
      hsh16[cur ^ 1][j] = (_Float16)h;
      int t = dir ? (SS - 1 - step) : step;
      hbuf[((size_t)b * SS + t) * (2 * HDIM) + dir * HDIM + j] = h;
    }
    __syncthreads();
    p0 = p1; p1 = p2;
    cur ^= 1;
  }
}

// ---------------- K4: emission = [h_f,h_b] @ proj_w^T + proj_b ----------------
__global__ void k_proj(const float* __restrict__ hbuf, const float* __restrict__ pw,
                       const float* __restrict__ pb, float* __restrict__ em) {
  int idx = blockIdx.x * blockDim.x + threadIdx.x;  // token*32 + tag
  if (idx >= BB * SS * NTAGS) return;
  int token = idx >> 5, tag = idx & 31;
  const float4* h4 = (const float4*)(hbuf + (size_t)token * 2 * HDIM);
  const float4* w4 = (const float4*)(pw + (size_t)tag * 2 * HDIM);
  float acc = pb[tag];
#pragma unroll 10
  for (int k = 0; k < 50; k++) {
    float4 hv = h4[k], wv = w4[k];
    acc += hv.x * wv.x + hv.y * wv.y + hv.z * wv.z + hv.w * wv.w;
  }
  em[idx] = acc;
}

// ---------------- K5: gold path score per batch ----------------
__global__ __launch_bounds__(64) void k_score(const float* __restrict__ em,
                                              const float* __restrict__ trans,
                                              const int* __restrict__ y,
                                              const int* __restrict__ mask,
                                              float* __restrict__ scoreY) {
  int b = blockIdx.x, l = threadIdx.x;
  float acc = 0.f;
  for (int s = l; s < SS; s += 64) {
    int curt = y[b * SS + s];
    int prevt = (s == 0) ? TAG_START : y[b * SS + s - 1];
    float mk = (float)mask[b * SS + s];
    acc += (em[((size_t)b * SS + s) * NTAGS + curt] + trans[prevt * NTAGS + curt]) * mk;
  }
#pragma unroll
  for (int off = 32; off > 0; off >>= 1) acc += __shfl_down(acc, off);
  if (l == 0) scoreY[b] = acc + trans[y[b * SS + SS - 1] * NTAGS + TAG_END];
}

// ---------------- K6: CRF forward (partition function) + loss ----------------
__global__ __launch_bounds__(64) void k_crf(const float* __restrict__ em,
                                            const float* __restrict__ trans,
                                            const int* __restrict__ mask,
                                            const float* __restrict__ scoreY,
                                            float* __restrict__ out) {
  int g = threadIdx.x >> 5;
  int j = threadIdx.x & 31;
  int b = blockIdx.x * 2 + g;
  float tcol[NTAGS];
#pragma unroll
  for (int i = 0; i < NTAGS; i++) tcol[i] = trans[i * NTAGS + j];
  float la = (j == TAG_START) ? 0.f : NEGV;
  __shared__ float lash[2][NTAGS];
  for (int s = 0; s < SS; s++) {
    lash[g][j] = la;
    __syncthreads();
    float emv = em[((size_t)b * SS + s) * NTAGS + j];
    float m = -3.0e38f;
#pragma unroll
    for (int i = 0; i < NTAGS; i++) m = fmaxf(m, lash[g][i] + tcol[i]);
    float sum = 0.f;
#pragma unroll
    for (int i = 0; i < NTAGS; i++) sum += __expf(lash[g][i] + tcol[i] - m);
    float la2 = m + __logf(sum) + emv;
    float mk = (float)mask[b * SS + s];
    la = la2 * mk + la * (1.f - mk);
    __syncthreads();
  }
  la += trans[j * NTAGS + TAG_END];
  lash[g][j] = la;
  __syncthreads();
  float m = -3.0e38f;
#pragma unroll
  for (int i = 0; i < NTAGS; i++) m = fmaxf(m, lash[g][i]);
  float sum = 0.f;
#pragma unroll
  for (int i = 0; i < NTAGS; i++) sum += __expf(lash[g][i] - m);
  float total = m + __logf(sum);
  if (j == 0) atomicAdd(out, (total - scoreY[b]) * (1.0f / BB));
}

extern "C" void kernel_launch(void* const* d_in, const int* in_sizes, int n_in,
                              void* d_out, int out_size, void* d_ws, size_t ws_size,
                              hipStream_t stream) {
  const float* word_emb = (const float*)d_in[0];
  const float* char_emb = (const float*)d_in[1];
  const float* conv_w   = (const float*)d_in[2];
  const float* conv_b   = (const float*)d_in[3];
  const float* wih_f    = (const float*)d_in[4];
  const float* whh_f    = (const float*)d_in[5];
  const float* bih_f    = (const float*)d_in[6];
  const float* bhh_f    = (const float*)d_in[7];
  const float* wih_b    = (const float*)d_in[8];
  const float* whh_b    = (const float*)d_in[9];
  const float* bih_b    = (const float*)d_in[10];
  const float* bhh_b    = (const float*)d_in[11];
  const float* proj_w   = (const float*)d_in[12];
  const float* proj_b   = (const float*)d_in[13];
  const float* trans    = (const float*)d_in[14];
  const int* word_x     = (const int*)d_in[15];
  const int* char_x     = (const int*)d_in[16];
  const int* y          = (const int*)d_in[17];
  const int* mask       = (const int*)d_in[18];
  float* out = (float*)d_out;

  float* ws = (float*)d_ws;
  float* x      = ws;                                  // 32768*130
  float* preF   = x + (size_t)BB * SS * KIN;           // 32768*400
  float* preB   = preF + (size_t)BB * SS * GDIM;       // 32768*400
  float* hbuf   = preB + (size_t)BB * SS * GDIM;       // 32768*200
  float* em     = hbuf + (size_t)BB * SS * 2 * HDIM;   // 32768*32
  float* scoreY = em + (size_t)BB * SS * NTAGS;        // 128

  hipMemsetAsync(d_out, 0, sizeof(float), stream);
  k_word<<<(BB * SS * WDIM + 255) / 256, 256, 0, stream>>>(word_emb, word_x, x);
  k_charconv<<<BB * SS / CTOK, 256, 0, stream>>>(char_emb, conv_w, conv_b, char_x, x);
  k_pregemm<<<dim3(BB * SS / 64, 13), 256, 0, stream>>>(x, wih_f, wih_b, bih_f, bhh_f,
                                                        bih_b, bhh_b, preF, preB);
  k_lstm<<<256, 512, 0, stream>>>(preF, preB, whh_f, whh_b, hbuf);
  k_proj<<<(BB * SS * NTAGS + 255) / 256, 256, 0, stream>>>(hbuf, proj_w, proj_b, em);
  k_score<<<BB, 64, 0, stream>>>(em, trans, y, mask, scoreY);
  k_crf<<<BB / 2, 64, 0, stream>>>(em, trans, mask, scoreY, out);
}